// Round 1
// baseline (1038.975 us; speedup 1.0000x reference)
//
#include <hip/hip_runtime.h>

// Problem constants (fixed by setup_inputs)
#define BATCH    4
#define NQ       10000
#define EMB      256
#define NH       8
#define DH       32
#define NL       4
#define NP       8
#define S_TOTAL  19560
#define NROW     (BATCH * NQ)          // 40000
#define VROWS    (BATCH * S_TOTAL)     // 78240

// ---------------------------------------------------------------------------
// Generic f32 GEMM: C[M,N] = A[M,256] @ W[256,N] + bias[N]
// Tile: 32 rows x 256 cols per block, 256 threads (thread t owns column
// n0+t for all 32 rows). A tile staged in LDS, read back as broadcast
// float4 (same address across lanes -> conflict-free broadcast).
// M must be a multiple of 32 (78240 and 40000 both are).
// ---------------------------------------------------------------------------
__global__ __launch_bounds__(256) void gemm_f32(
    const float* __restrict__ A, const float* __restrict__ W,
    const float* __restrict__ bias, float* __restrict__ C, int N) {
  __shared__ float a_s[32 * 256];
  const int t  = threadIdx.x;
  const int r0 = blockIdx.x * 32;
  const int n  = blockIdx.y * 256 + t;

  #pragma unroll
  for (int j = 0; j < 32; ++j)
    a_s[j * 256 + t] = A[(size_t)(r0 + j) * 256 + t];
  __syncthreads();

  float acc[32];
  const float b = bias[n];
  #pragma unroll
  for (int r = 0; r < 32; ++r) acc[r] = b;

  for (int k0 = 0; k0 < 256; k0 += 4) {
    const float w0 = W[(size_t)(k0 + 0) * N + n];
    const float w1 = W[(size_t)(k0 + 1) * N + n];
    const float w2 = W[(size_t)(k0 + 2) * N + n];
    const float w3 = W[(size_t)(k0 + 3) * N + n];
    #pragma unroll
    for (int r = 0; r < 32; ++r) {
      const float4 a = *(const float4*)&a_s[r * 256 + k0];
      acc[r] = fmaf(a.x, w0, acc[r]);
      acc[r] = fmaf(a.y, w1, acc[r]);
      acc[r] = fmaf(a.z, w2, acc[r]);
      acc[r] = fmaf(a.w, w3, acc[r]);
    }
  }

  #pragma unroll
  for (int r = 0; r < 32; ++r)
    C[(size_t)(r0 + r) * N + n] = acc[r];
}

// ---------------------------------------------------------------------------
// Fused softmax + deformable bilinear sampling.
// One block per (b,q). Phase 1: thread t = (h,l,p) combo -> softmax weight,
// 4 clamped gather bases, 4 masked bilinear*attn weights into LDS.
// Phase 2: thread t = (h,d) accumulates 32 points x 4 corners.
// Gathers are 128B-contiguous per 32-lane head group (d fastest in vproj).
// ---------------------------------------------------------------------------
__global__ __launch_bounds__(256) void msda_sample(
    const float* __restrict__ vproj,   // [B*S, 256] (d fastest, h*32+d)
    const float* __restrict__ off,     // [B*Q, 512]
    const float* __restrict__ logits,  // [B*Q, 256]
    const float* __restrict__ ref,     // [B*Q, 4, 2]
    float* __restrict__ out) {         // [B*Q, 256]
  const int lvl_h[NL] = {92, 46, 23, 12};
  const int lvl_w[NL] = {160, 80, 40, 20};
  const int lvl_s[NL] = {0, 14720, 18400, 19320};

  __shared__ float red_s[256];
  __shared__ float4 w_s[256];
  __shared__ int4   a_s[256];

  const int t   = threadIdx.x;
  const int row = blockIdx.x;          // b*NQ + q
  const int b   = row / NQ;

  const int h  = t >> 5;
  const int lp = t & 31;
  const int l  = lp >> 3;
  const int p  = lp & 7;

  // ---- softmax over the 32 (l,p) logits of this head ----
  const float logit = logits[(size_t)row * 256 + t];
  red_s[t] = logit;
  __syncthreads();
  float mx = -1e30f;
  #pragma unroll
  for (int j = 0; j < 32; ++j) mx = fmaxf(mx, red_s[(h << 5) + j]);
  const float e = __expf(logit - mx);
  __syncthreads();
  red_s[t] = e;
  __syncthreads();
  float sum = 0.f;
  #pragma unroll
  for (int j = 0; j < 32; ++j) sum += red_s[(h << 5) + j];
  const float attnw = e / sum;

  // ---- location & bilinear setup ----
  const float2 o = *(const float2*)&off[(size_t)row * 512 + 2 * t];
  const int z = p & 3;                       // NP=8 split (2,4): z = p % 4
  const float rx = ref[((size_t)row * 4 + z) * 2 + 0];
  const float ry = ref[((size_t)row * 4 + z) * 2 + 1];
  const int Wl = lvl_w[l], Hl = lvl_h[l], st = lvl_s[l];

  const float px = fmaf(rx, (float)Wl, o.x) - 0.5f;
  const float py = fmaf(ry, (float)Hl, o.y) - 0.5f;
  const float x0f = floorf(px), y0f = floorf(py);
  const float wx = px - x0f, wy = py - y0f;
  const int x0 = (int)x0f, y0 = (int)y0f;
  const int x1 = x0 + 1,   y1 = y0 + 1;

  const float mx0 = (x0 >= 0 && x0 < Wl) ? 1.f : 0.f;
  const float mx1 = (x1 >= 0 && x1 < Wl) ? 1.f : 0.f;
  const float my0 = (y0 >= 0 && y0 < Hl) ? 1.f : 0.f;
  const float my1 = (y1 >= 0 && y1 < Hl) ? 1.f : 0.f;
  const int cx0 = min(max(x0, 0), Wl - 1), cx1 = min(max(x1, 0), Wl - 1);
  const int cy0 = min(max(y0, 0), Hl - 1), cy1 = min(max(y1, 0), Hl - 1);

  const int base = b * S_TOTAL + st;
  const int hoff = h << 5;
  int4 a4;
  a4.x = (base + cy0 * Wl + cx0) * 256 + hoff;
  a4.y = (base + cy0 * Wl + cx1) * 256 + hoff;
  a4.z = (base + cy1 * Wl + cx0) * 256 + hoff;
  a4.w = (base + cy1 * Wl + cx1) * 256 + hoff;

  float4 w4;
  w4.x = attnw * (1.f - wx) * (1.f - wy) * mx0 * my0;
  w4.y = attnw * wx * (1.f - wy) * mx1 * my0;
  w4.z = attnw * (1.f - wx) * wy * mx0 * my1;
  w4.w = attnw * wx * wy * mx1 * my1;

  w_s[t] = w4;
  a_s[t] = a4;
  __syncthreads();

  // ---- accumulate: thread t = (h, d) ----
  const int d = t & 31;
  float acc = 0.f;
  #pragma unroll 4
  for (int i = 0; i < 32; ++i) {
    const float4 w = w_s[(h << 5) + i];
    const int4  a = a_s[(h << 5) + i];
    acc = fmaf(w.x, vproj[a.x + d], acc);
    acc = fmaf(w.y, vproj[a.y + d], acc);
    acc = fmaf(w.z, vproj[a.z + d], acc);
    acc = fmaf(w.w, vproj[a.w + d], acc);
  }
  out[(size_t)row * 256 + t] = acc;
}

extern "C" void kernel_launch(void* const* d_in, const int* in_sizes, int n_in,
                              void* d_out, int out_size, void* d_ws, size_t ws_size,
                              hipStream_t stream) {
  const float* query  = (const float*)d_in[0];  // [4,10000,256]
  const float* value  = (const float*)d_in[1];  // [4,19560,256]
  const float* refpts = (const float*)d_in[2];  // [4,10000,4,2]
  const float* w_off  = (const float*)d_in[3];  // [256,512]
  const float* b_off  = (const float*)d_in[4];  // [512]
  const float* w_attn = (const float*)d_in[5];  // [256,256]
  const float* b_attn = (const float*)d_in[6];  // [256]
  const float* w_val  = (const float*)d_in[7];  // [256,256]
  const float* b_val  = (const float*)d_in[8];  // [256]
  float* out = (float*)d_out;

  float* v_ws     = (float*)d_ws;                       // 78240*256
  float* off_ws   = v_ws + (size_t)VROWS * 256;         // 40000*512
  float* logit_ws = off_ws + (size_t)NROW * 512;        // 40000*256

  // v = value @ w_val + b_val
  gemm_f32<<<dim3(VROWS / 32, 1), 256, 0, stream>>>(value, w_val, b_val, v_ws, 256);
  // off = query @ w_off + b_off
  gemm_f32<<<dim3(NROW / 32, 2), 256, 0, stream>>>(query, w_off, b_off, off_ws, 512);
  // logits = query @ w_attn + b_attn
  gemm_f32<<<dim3(NROW / 32, 1), 256, 0, stream>>>(query, w_attn, b_attn, logit_ws, 256);
  // softmax + sample + weighted sum
  msda_sample<<<dim3(NROW), 256, 0, stream>>>(v_ws, off_ws, logit_ws, refpts, out);
}

// Round 2
// 590.287 us; speedup vs baseline: 1.7601x; 1.7601x over previous
//
#include <hip/hip_runtime.h>

// Problem constants (fixed by setup_inputs)
#define BATCH    4
#define NQ       10000
#define EMB      256
#define NH       8
#define DH       32
#define NL       4
#define NP       8
#define S_TOTAL  19560
#define NROW     (BATCH * NQ)          // 40000  (= 625 * 64)
#define VROWS    (BATCH * S_TOTAL)     // 78240  (NOT mult of 64)
#define VROWS_P  78272                 // 1223 * 64

typedef _Float16 half8 __attribute__((ext_vector_type(8)));
typedef _Float16 half2v __attribute__((ext_vector_type(2)));
typedef float floatx4 __attribute__((ext_vector_type(4)));

// ---------------------------------------------------------------------------
// f32 -> f16 row-major copy with zero row padding. 8 elems per thread.
// ---------------------------------------------------------------------------
__global__ __launch_bounds__(256) void conv_f16(
    const float* __restrict__ in, _Float16* __restrict__ out, int M, int Mpad) {
  const size_t e = ((size_t)blockIdx.x * 256 + threadIdx.x) * 8;
  if (e >= (size_t)Mpad * 256) return;
  half8 h;
  if ((int)(e >> 8) < M) {
    const float4 f0 = *(const float4*)(in + e);
    const float4 f1 = *(const float4*)(in + e + 4);
    h[0] = (_Float16)f0.x; h[1] = (_Float16)f0.y;
    h[2] = (_Float16)f0.z; h[3] = (_Float16)f0.w;
    h[4] = (_Float16)f1.x; h[5] = (_Float16)f1.y;
    h[6] = (_Float16)f1.z; h[7] = (_Float16)f1.w;
  } else {
    h = (half8)0;
  }
  *(half8*)(out + e) = h;
}

// ---------------------------------------------------------------------------
// W[256,N] f32 -> WT[N,256] f16 (weights are tiny; strided reads ok)
// ---------------------------------------------------------------------------
__global__ __launch_bounds__(256) void transp_f16(
    const float* __restrict__ W, _Float16* __restrict__ WT, int N) {
  const int tid = blockIdx.x * 256 + threadIdx.x;   // over N*256
  const int n = tid >> 8, k = tid & 255;
  WT[(size_t)n * 256 + k] = (_Float16)W[(size_t)k * N + n];
}

// ---------------------------------------------------------------------------
// MFMA GEMM: C[M,Nc] = A[Mpad,256]_f16 @ WT[Nc,256]_f16^T + bias.
// Block: 256 thr = 4 waves; block computes 64 rows x 256 cols
// (wave w -> cols n0 + 64w). Wave: 4x4 grid of 16x16x32 MFMA tiles, K=256.
// A frag: lane holds A[m0+16i + (lane&15)][k + (lane>>4)*8 + 0..7]  (16B load)
// B frag: lane holds WT[n0+16j + (lane&15)][k + (lane>>4)*8 + 0..7] (16B load)
// C/D:    reg r holds C[16i + (lane>>4)*4 + r][16j + (lane&15)]
// ---------------------------------------------------------------------------
template <typename OutT>
__global__ __launch_bounds__(256) void gemm_mfma(
    const _Float16* __restrict__ A, const _Float16* __restrict__ WT,
    const float* __restrict__ bias, OutT* __restrict__ C, int M, int Nc) {
  const int t = threadIdx.x;
  const int wave = t >> 6, lane = t & 63;
  const int l15 = lane & 15, quad = lane >> 4;
  const int m0 = blockIdx.x * 64;
  const int n0 = blockIdx.y * 256 + wave * 64;

  const _Float16* Ab = A + (size_t)(m0 + l15) * 256 + quad * 8;
  const _Float16* Bb = WT + (size_t)(n0 + l15) * 256 + quad * 8;

  floatx4 acc[4][4] = {};

  #pragma unroll 2
  for (int k = 0; k < 256; k += 32) {
    half8 a[4], b[4];
    #pragma unroll
    for (int i = 0; i < 4; ++i) a[i] = *(const half8*)(Ab + i * (16 * 256) + k);
    #pragma unroll
    for (int j = 0; j < 4; ++j) b[j] = *(const half8*)(Bb + j * (16 * 256) + k);
    #pragma unroll
    for (int i = 0; i < 4; ++i)
      #pragma unroll
      for (int j = 0; j < 4; ++j)
        acc[i][j] = __builtin_amdgcn_mfma_f32_16x16x32_f16(a[i], b[j], acc[i][j], 0, 0, 0);
  }

  #pragma unroll
  for (int i = 0; i < 4; ++i) {
    #pragma unroll
    for (int r = 0; r < 4; ++r) {
      const int row = m0 + 16 * i + quad * 4 + r;
      if (row < M) {
        #pragma unroll
        for (int j = 0; j < 4; ++j) {
          const int col = n0 + 16 * j + l15;
          C[(size_t)row * Nc + col] = (OutT)(acc[i][j][r] + bias[col]);
        }
      }
    }
  }
}

// ---------------------------------------------------------------------------
// Fused softmax + deformable bilinear sampling (unchanged structure;
// off/logits now f16).
// ---------------------------------------------------------------------------
__global__ __launch_bounds__(256) void msda_sample(
    const float* __restrict__ vproj,        // [B*S, 256] f32 (d fastest)
    const _Float16* __restrict__ off,       // [B*Q, 512] f16
    const _Float16* __restrict__ logits,    // [B*Q, 256] f16
    const float* __restrict__ ref,          // [B*Q, 4, 2] f32
    float* __restrict__ out) {              // [B*Q, 256] f32
  const int lvl_h[NL] = {92, 46, 23, 12};
  const int lvl_w[NL] = {160, 80, 40, 20};
  const int lvl_s[NL] = {0, 14720, 18400, 19320};

  __shared__ float red_s[256];
  __shared__ float4 w_s[256];
  __shared__ int4   a_s[256];

  const int t   = threadIdx.x;
  const int row = blockIdx.x;          // b*NQ + q
  const int b   = row / NQ;

  const int h  = t >> 5;
  const int lp = t & 31;
  const int l  = lp >> 3;
  const int p  = lp & 7;

  // ---- softmax over the 32 (l,p) logits of this head ----
  const float logit = (float)logits[(size_t)row * 256 + t];
  red_s[t] = logit;
  __syncthreads();
  float mx = -1e30f;
  #pragma unroll
  for (int j = 0; j < 32; ++j) mx = fmaxf(mx, red_s[(h << 5) + j]);
  const float e = __expf(logit - mx);
  __syncthreads();
  red_s[t] = e;
  __syncthreads();
  float sum = 0.f;
  #pragma unroll
  for (int j = 0; j < 32; ++j) sum += red_s[(h << 5) + j];
  const float attnw = e / sum;

  // ---- location & bilinear setup ----
  const half2v o2 = *(const half2v*)(off + (size_t)row * 512 + 2 * t);
  const float ox = (float)o2[0], oy = (float)o2[1];
  const int z = p & 3;                       // NP=8 split (2,4): z = p % 4
  const float rx = ref[((size_t)row * 4 + z) * 2 + 0];
  const float ry = ref[((size_t)row * 4 + z) * 2 + 1];
  const int Wl = lvl_w[l], Hl = lvl_h[l], st = lvl_s[l];

  const float px = fmaf(rx, (float)Wl, ox) - 0.5f;
  const float py = fmaf(ry, (float)Hl, oy) - 0.5f;
  const float x0f = floorf(px), y0f = floorf(py);
  const float wx = px - x0f, wy = py - y0f;
  const int x0 = (int)x0f, y0 = (int)y0f;
  const int x1 = x0 + 1,   y1 = y0 + 1;

  const float mx0 = (x0 >= 0 && x0 < Wl) ? 1.f : 0.f;
  const float mx1 = (x1 >= 0 && x1 < Wl) ? 1.f : 0.f;
  const float my0 = (y0 >= 0 && y0 < Hl) ? 1.f : 0.f;
  const float my1 = (y1 >= 0 && y1 < Hl) ? 1.f : 0.f;
  const int cx0 = min(max(x0, 0), Wl - 1), cx1 = min(max(x1, 0), Wl - 1);
  const int cy0 = min(max(y0, 0), Hl - 1), cy1 = min(max(y1, 0), Hl - 1);

  const int base = b * S_TOTAL + st;
  const int hoff = h << 5;
  int4 a4;
  a4.x = (base + cy0 * Wl + cx0) * 256 + hoff;
  a4.y = (base + cy0 * Wl + cx1) * 256 + hoff;
  a4.z = (base + cy1 * Wl + cx0) * 256 + hoff;
  a4.w = (base + cy1 * Wl + cx1) * 256 + hoff;

  float4 w4;
  w4.x = attnw * (1.f - wx) * (1.f - wy) * mx0 * my0;
  w4.y = attnw * wx * (1.f - wy) * mx1 * my0;
  w4.z = attnw * (1.f - wx) * wy * mx0 * my1;
  w4.w = attnw * wx * wy * mx1 * my1;

  w_s[t] = w4;
  a_s[t] = a4;
  __syncthreads();

  // ---- accumulate: thread t = (h, d) ----
  const int d = t & 31;
  float acc = 0.f;
  #pragma unroll 4
  for (int i = 0; i < 32; ++i) {
    const float4 w = w_s[(h << 5) + i];
    const int4  a = a_s[(h << 5) + i];
    acc = fmaf(w.x, vproj[a.x + d], acc);
    acc = fmaf(w.y, vproj[a.y + d], acc);
    acc = fmaf(w.z, vproj[a.z + d], acc);
    acc = fmaf(w.w, vproj[a.w + d], acc);
  }
  out[(size_t)row * 256 + t] = acc;
}

extern "C" void kernel_launch(void* const* d_in, const int* in_sizes, int n_in,
                              void* d_out, int out_size, void* d_ws, size_t ws_size,
                              hipStream_t stream) {
  const float* query  = (const float*)d_in[0];  // [4,10000,256]
  const float* value  = (const float*)d_in[1];  // [4,19560,256]
  const float* refpts = (const float*)d_in[2];  // [4,10000,4,2]
  const float* w_off  = (const float*)d_in[3];  // [256,512]
  const float* b_off  = (const float*)d_in[4];  // [512]
  const float* w_attn = (const float*)d_in[5];  // [256,256]
  const float* b_attn = (const float*)d_in[6];  // [256]
  const float* w_val  = (const float*)d_in[7];  // [256,256]
  const float* b_val  = (const float*)d_in[8];  // [256]
  float* out = (float*)d_out;

  // workspace layout (all segment sizes 16B-multiples)
  char* p = (char*)d_ws;
  float* v_ws = (float*)p;            p += (size_t)VROWS * 256 * 4;      // 80.1 MB
  _Float16* vh   = (_Float16*)p;      p += (size_t)VROWS_P * 256 * 2;    // 40.1 MB
  _Float16* qh   = (_Float16*)p;      p += (size_t)NROW * 256 * 2;       // 20.5 MB
  _Float16* wofT = (_Float16*)p;      p += (size_t)512 * 256 * 2;
  _Float16* watT = (_Float16*)p;      p += (size_t)256 * 256 * 2;
  _Float16* wvaT = (_Float16*)p;      p += (size_t)256 * 256 * 2;
  _Float16* off_h = (_Float16*)p;     p += (size_t)NROW * 512 * 2;       // 41.0 MB
  _Float16* log_h = (_Float16*)p;     p += (size_t)NROW * 256 * 2;       // 20.5 MB

  // f32 -> f16 staging
  conv_f16<<<NROW * 256 / 8 / 256, 256, 0, stream>>>(query, qh, NROW, NROW);
  conv_f16<<<VROWS_P * 256 / 8 / 256, 256, 0, stream>>>(value, vh, VROWS, VROWS_P);
  transp_f16<<<512, 256, 0, stream>>>(w_off, wofT, 512);
  transp_f16<<<256, 256, 0, stream>>>(w_attn, watT, 256);
  transp_f16<<<256, 256, 0, stream>>>(w_val, wvaT, 256);

  // MFMA GEMMs
  gemm_mfma<float><<<dim3(VROWS_P / 64, 1), 256, 0, stream>>>(
      vh, wvaT, b_val, v_ws, VROWS, 256);
  gemm_mfma<_Float16><<<dim3(NROW / 64, 2), 256, 0, stream>>>(
      qh, wofT, b_off, off_h, NROW, 512);
  gemm_mfma<_Float16><<<dim3(NROW / 64, 1), 256, 0, stream>>>(
      qh, watT, b_attn, log_h, NROW, 256);

  // softmax + sample + weighted sum
  msda_sample<<<dim3(NROW), 256, 0, stream>>>(v_ws, off_h, log_h, refpts, out);
}

// Round 3
// 526.326 us; speedup vs baseline: 1.9740x; 1.1215x over previous
//
#include <hip/hip_runtime.h>

// Problem constants (fixed by setup_inputs)
#define BATCH    4
#define NQ       10000
#define EMB      256
#define NH       8
#define DH       32
#define NL       4
#define NP       8
#define S_TOTAL  19560
#define NROW     (BATCH * NQ)          // 40000  (= 625 * 64)
#define VROWS    (BATCH * S_TOTAL)     // 78240  (NOT mult of 64)
#define VROWS_P  78272                 // 1223 * 64

typedef _Float16 half8 __attribute__((ext_vector_type(8)));
typedef _Float16 half2v __attribute__((ext_vector_type(2)));
typedef float floatx4 __attribute__((ext_vector_type(4)));

// ---------------------------------------------------------------------------
// W[256,N] f32 -> WT[N,256] f16 (weights are tiny; strided reads hit L2)
// ---------------------------------------------------------------------------
__global__ __launch_bounds__(256) void transp_f16(
    const float* __restrict__ W, _Float16* __restrict__ WT, int N) {
  const int tid = blockIdx.x * 256 + threadIdx.x;   // over N*256
  const int n = tid >> 8, k = tid & 255;
  WT[(size_t)n * 256 + k] = (_Float16)W[(size_t)k * N + n];
}

// ---------------------------------------------------------------------------
// MFMA GEMM: C[M,Nc] = A[M,256]_f32 @ WT[Nc,256]_f16^T + bias.
// A read as f32, converted to f16 in-register (no staging pass).
// Register double-buffer on the K loop to hide L2 latency.
// Block: 256 thr = 4 waves; block = 64 rows x 256 cols (wave w -> cols +64w).
// Wave: 4x4 grid of 16x16x32 MFMA tiles, K=256.
//   A frag: lane holds A[m0+16i + (lane&15)][quad*8 + k .. +7]
//   B frag: lane holds WT[n0+16j + (lane&15)][quad*8 + k .. +7]
//   C/D:    reg r -> C[16i + quad*4 + r][16j + (lane&15)]
// Rows clamped to M-1 for the padded tail tile (stores guarded by row<M).
// ---------------------------------------------------------------------------
template <typename OutT>
__global__ __launch_bounds__(256) void gemm_mfma(
    const float* __restrict__ A, const _Float16* __restrict__ WT,
    const float* __restrict__ bias, OutT* __restrict__ C, int M, int Nc) {
  const int t = threadIdx.x;
  const int wave = t >> 6, lane = t & 63;
  const int l15 = lane & 15, quad = lane >> 4;
  const int m0 = blockIdx.x * 64;
  const int n0 = blockIdx.y * 256 + wave * 64;

  const float* Ab[4];
  #pragma unroll
  for (int i = 0; i < 4; ++i) {
    const int row = min(m0 + 16 * i + l15, M - 1);
    Ab[i] = A + (size_t)row * 256 + quad * 8;
  }
  const _Float16* Bb = WT + (size_t)(n0 + l15) * 256 + quad * 8;

  floatx4 acc[4][4] = {};

  float4 ar[4][2];
  half8  br[4];
  #pragma unroll
  for (int i = 0; i < 4; ++i) {
    ar[i][0] = *(const float4*)(Ab[i]);
    ar[i][1] = *(const float4*)(Ab[i] + 4);
  }
  #pragma unroll
  for (int j = 0; j < 4; ++j) br[j] = *(const half8*)(Bb + j * (16 * 256));

  #pragma unroll
  for (int ks = 0; ks < 8; ++ks) {
    const int kn = (ks + 1) * 32;
    float4 an[4][2];
    half8  bn[4];
    if (ks < 7) {
      #pragma unroll
      for (int i = 0; i < 4; ++i) {
        an[i][0] = *(const float4*)(Ab[i] + kn);
        an[i][1] = *(const float4*)(Ab[i] + kn + 4);
      }
      #pragma unroll
      for (int j = 0; j < 4; ++j) bn[j] = *(const half8*)(Bb + j * (16 * 256) + kn);
    }
    half8 ah[4];
    #pragma unroll
    for (int i = 0; i < 4; ++i) {
      ah[i][0] = (_Float16)ar[i][0].x; ah[i][1] = (_Float16)ar[i][0].y;
      ah[i][2] = (_Float16)ar[i][0].z; ah[i][3] = (_Float16)ar[i][0].w;
      ah[i][4] = (_Float16)ar[i][1].x; ah[i][5] = (_Float16)ar[i][1].y;
      ah[i][6] = (_Float16)ar[i][1].z; ah[i][7] = (_Float16)ar[i][1].w;
    }
    #pragma unroll
    for (int i = 0; i < 4; ++i)
      #pragma unroll
      for (int j = 0; j < 4; ++j)
        acc[i][j] = __builtin_amdgcn_mfma_f32_16x16x32_f16(ah[i], br[j], acc[i][j], 0, 0, 0);
    if (ks < 7) {
      #pragma unroll
      for (int i = 0; i < 4; ++i) { ar[i][0] = an[i][0]; ar[i][1] = an[i][1]; }
      #pragma unroll
      for (int j = 0; j < 4; ++j) br[j] = bn[j];
    }
  }

  #pragma unroll
  for (int i = 0; i < 4; ++i) {
    #pragma unroll
    for (int r = 0; r < 4; ++r) {
      const int row = m0 + 16 * i + quad * 4 + r;
      if (row < M) {
        #pragma unroll
        for (int j = 0; j < 4; ++j) {
          const int col = n0 + 16 * j + l15;
          C[(size_t)row * Nc + col] = (OutT)(acc[i][j][r] + bias[col]);
        }
      }
    }
  }
}

// ---------------------------------------------------------------------------
// Fused softmax + deformable bilinear sampling.
// One block per (b,q). Phase 1: thread t = (h,l,p) -> softmax weight (xor-
// shuffle within the 32-lane head group), 4 gather element-offsets + 4
// bilinear*attn weights into LDS. Phase 2: thread t = (h, pt_half, ch_pair):
// 16 lanes cover the head's 32 channels as half2, 2-way parallel over
// points; __shfl_xor(.,16) combines the two point halves.
// vproj is f16: each 16-lane gather group reads 64 B contiguous per corner.
// ---------------------------------------------------------------------------
__global__ __launch_bounds__(256) void msda_sample(
    const _Float16* __restrict__ vproj,     // [B*S, 256] f16 (d fastest)
    const _Float16* __restrict__ off,       // [B*Q, 512] f16
    const _Float16* __restrict__ logits,    // [B*Q, 256] f16
    const float* __restrict__ ref,          // [B*Q, 4, 2] f32
    float* __restrict__ out) {              // [B*Q, 256] f32
  const int lvl_h[NL] = {92, 46, 23, 12};
  const int lvl_w[NL] = {160, 80, 40, 20};
  const int lvl_s[NL] = {0, 14720, 18400, 19320};

  __shared__ float4 w_s[256];
  __shared__ int4   a_s[256];

  const int t   = threadIdx.x;
  const int row = blockIdx.x;          // b*NQ + q
  const int b   = row / NQ;

  const int h  = t >> 5;
  const int lp = t & 31;
  const int l  = lp >> 3;
  const int p  = lp & 7;

  // ---- softmax over the 32 (l,p) logits of this head (xor shuffles) ----
  const float logit = (float)logits[(size_t)row * 256 + t];
  float mx = logit;
  #pragma unroll
  for (int m = 1; m < 32; m <<= 1) mx = fmaxf(mx, __shfl_xor(mx, m));
  const float e = __expf(logit - mx);
  float sum = e;
  #pragma unroll
  for (int m = 1; m < 32; m <<= 1) sum += __shfl_xor(sum, m);
  const float attnw = e / sum;

  // ---- location & bilinear setup ----
  const half2v o2 = *(const half2v*)(off + (size_t)row * 512 + 2 * t);
  const float ox = (float)o2[0], oy = (float)o2[1];
  const int z = p & 3;                       // NP=8 split (2,4): z = p % 4
  const float rx = ref[((size_t)row * 4 + z) * 2 + 0];
  const float ry = ref[((size_t)row * 4 + z) * 2 + 1];
  const int Wl = lvl_w[l], Hl = lvl_h[l], st = lvl_s[l];

  const float px = fmaf(rx, (float)Wl, ox) - 0.5f;
  const float py = fmaf(ry, (float)Hl, oy) - 0.5f;
  const float x0f = floorf(px), y0f = floorf(py);
  const float wx = px - x0f, wy = py - y0f;
  const int x0 = (int)x0f, y0 = (int)y0f;
  const int x1 = x0 + 1,   y1 = y0 + 1;

  const float mx0 = (x0 >= 0 && x0 < Wl) ? 1.f : 0.f;
  const float mx1 = (x1 >= 0 && x1 < Wl) ? 1.f : 0.f;
  const float my0 = (y0 >= 0 && y0 < Hl) ? 1.f : 0.f;
  const float my1 = (y1 >= 0 && y1 < Hl) ? 1.f : 0.f;
  const int cx0 = min(max(x0, 0), Wl - 1), cx1 = min(max(x1, 0), Wl - 1);
  const int cy0 = min(max(y0, 0), Hl - 1), cy1 = min(max(y1, 0), Hl - 1);

  const int base = b * S_TOTAL + st;
  const int hoff = h << 5;
  int4 a4;
  a4.x = (base + cy0 * Wl + cx0) * 256 + hoff;
  a4.y = (base + cy0 * Wl + cx1) * 256 + hoff;
  a4.z = (base + cy1 * Wl + cx0) * 256 + hoff;
  a4.w = (base + cy1 * Wl + cx1) * 256 + hoff;

  float4 w4;
  w4.x = attnw * (1.f - wx) * (1.f - wy) * mx0 * my0;
  w4.y = attnw * wx * (1.f - wy) * mx1 * my0;
  w4.z = attnw * (1.f - wx) * wy * mx0 * my1;
  w4.w = attnw * wx * wy * mx1 * my1;

  w_s[t] = w4;
  a_s[t] = a4;
  __syncthreads();

  // ---- accumulate: thread t = (h, pt_half, ch_pair) ----
  const int ph = (t >> 4) & 1;          // which half of the 32 points
  const int dp = t & 15;                // channel pair: channels 2dp, 2dp+1
  const _Float16* vp2 = vproj + 2 * dp;
  float acc0 = 0.f, acc1 = 0.f;
  #pragma unroll 8
  for (int i = 0; i < 16; ++i) {
    const int pt = (h << 5) + (ph << 4) + i;
    const float4 w = w_s[pt];
    const int4  a = a_s[pt];
    const half2v v0 = *(const half2v*)(vp2 + a.x);
    const half2v v1 = *(const half2v*)(vp2 + a.y);
    const half2v v2 = *(const half2v*)(vp2 + a.z);
    const half2v v3 = *(const half2v*)(vp2 + a.w);
    acc0 = fmaf(w.x, (float)v0[0], acc0); acc1 = fmaf(w.x, (float)v0[1], acc1);
    acc0 = fmaf(w.y, (float)v1[0], acc0); acc1 = fmaf(w.y, (float)v1[1], acc1);
    acc0 = fmaf(w.z, (float)v2[0], acc0); acc1 = fmaf(w.z, (float)v2[1], acc1);
    acc0 = fmaf(w.w, (float)v3[0], acc0); acc1 = fmaf(w.w, (float)v3[1], acc1);
  }
  // combine the two point halves (lanes l and l^16 are the same head)
  acc0 += __shfl_xor(acc0, 16);
  acc1 += __shfl_xor(acc1, 16);
  if (ph == 0) {
    float2 o; o.x = acc0; o.y = acc1;
    *(float2*)(out + (size_t)row * 256 + hoff + 2 * dp) = o;
  }
}

extern "C" void kernel_launch(void* const* d_in, const int* in_sizes, int n_in,
                              void* d_out, int out_size, void* d_ws, size_t ws_size,
                              hipStream_t stream) {
  const float* query  = (const float*)d_in[0];  // [4,10000,256]
  const float* value  = (const float*)d_in[1];  // [4,19560,256]
  const float* refpts = (const float*)d_in[2];  // [4,10000,4,2]
  const float* w_off  = (const float*)d_in[3];  // [256,512]
  const float* b_off  = (const float*)d_in[4];  // [512]
  const float* w_attn = (const float*)d_in[5];  // [256,256]
  const float* b_attn = (const float*)d_in[6];  // [256]
  const float* w_val  = (const float*)d_in[7];  // [256,256]
  const float* b_val  = (const float*)d_in[8];  // [256]
  float* out = (float*)d_out;

  // workspace layout (all segment sizes 16B-multiples)
  char* p = (char*)d_ws;
  _Float16* vh   = (_Float16*)p;      p += (size_t)VROWS * 256 * 2;      // 40.1 MB
  _Float16* wofT = (_Float16*)p;      p += (size_t)512 * 256 * 2;
  _Float16* watT = (_Float16*)p;      p += (size_t)256 * 256 * 2;
  _Float16* wvaT = (_Float16*)p;      p += (size_t)256 * 256 * 2;
  _Float16* off_h = (_Float16*)p;     p += (size_t)NROW * 512 * 2;       // 41.0 MB
  _Float16* log_h = (_Float16*)p;     p += (size_t)NROW * 256 * 2;       // 20.5 MB

  // weight transposes (f32 -> f16)
  transp_f16<<<512, 256, 0, stream>>>(w_off, wofT, 512);
  transp_f16<<<256, 256, 0, stream>>>(w_attn, watT, 256);
  transp_f16<<<256, 256, 0, stream>>>(w_val, wvaT, 256);

  // MFMA GEMMs (A read as f32 directly, converted in-register)
  gemm_mfma<_Float16><<<dim3(VROWS_P / 64, 1), 256, 0, stream>>>(
      value, wvaT, b_val, vh, VROWS, 256);
  gemm_mfma<_Float16><<<dim3(NROW / 64, 2), 256, 0, stream>>>(
      query, wofT, b_off, off_h, NROW, 512);
  gemm_mfma<_Float16><<<dim3(NROW / 64, 1), 256, 0, stream>>>(
      query, watT, b_attn, log_h, NROW, 256);

  // softmax + sample + weighted sum
  msda_sample<<<dim3(NROW), 256, 0, stream>>>(vh, off_h, log_h, refpts, out);
}

// Round 4
// 493.324 us; speedup vs baseline: 2.1061x; 1.0669x over previous
//
#include <hip/hip_runtime.h>

// Problem constants (fixed by setup_inputs)
#define BATCH    4
#define NQ       10000
#define EMB      256
#define NH       8
#define DH       32
#define NL       4
#define NP       8
#define S_TOTAL  19560
#define NROW     (BATCH * NQ)          // 40000
#define VROWS    (BATCH * S_TOTAL)     // 78240

typedef _Float16 half8 __attribute__((ext_vector_type(8)));
typedef _Float16 half2v __attribute__((ext_vector_type(2)));
typedef float floatx4 __attribute__((ext_vector_type(4)));

// ---------------------------------------------------------------------------
// f32 -> f16 row-major copy. 8 elems per thread.
// ---------------------------------------------------------------------------
__global__ __launch_bounds__(256) void conv_f16(
    const float* __restrict__ in, _Float16* __restrict__ out, size_t total) {
  const size_t e = ((size_t)blockIdx.x * 256 + threadIdx.x) * 8;
  if (e >= total) return;
  const float4 f0 = *(const float4*)(in + e);
  const float4 f1 = *(const float4*)(in + e + 4);
  half8 h;
  h[0] = (_Float16)f0.x; h[1] = (_Float16)f0.y;
  h[2] = (_Float16)f0.z; h[3] = (_Float16)f0.w;
  h[4] = (_Float16)f1.x; h[5] = (_Float16)f1.y;
  h[6] = (_Float16)f1.z; h[7] = (_Float16)f1.w;
  *(half8*)(out + e) = h;
}

// ---------------------------------------------------------------------------
// W[256,N] f32 -> WT[N,256] f16
// ---------------------------------------------------------------------------
__global__ __launch_bounds__(256) void transp_f16(
    const float* __restrict__ W, _Float16* __restrict__ WT, int N) {
  const int tid = blockIdx.x * 256 + threadIdx.x;   // over N*256
  const int n = tid >> 8, k = tid & 255;
  WT[(size_t)n * 256 + k] = (_Float16)W[(size_t)k * N + n];
}

// fused bias [768] = concat(b_off[512], b_attn[256])
__global__ __launch_bounds__(256) void bias_cat(
    const float* __restrict__ b0, const float* __restrict__ b1,
    float* __restrict__ o) {
  const int t = blockIdx.x * 256 + threadIdx.x;
  if (t < 512) o[t] = b0[t];
  else if (t < 768) o[t] = b1[t - 512];
}

// ---------------------------------------------------------------------------
// MFMA GEMM, B-slab-in-LDS: C[M,NC] = A[M,256]_f16 @ WT[NC,256]^T + bias.
// Block: 256 thr = 4 waves stacked (wave w -> rows m0+64w..+63), block tile
// 256 rows x 128 cols. The block's full B slab (128 x 256 f16) sits in LDS
// with +8 f16/row padding (528B stride == 4-bank shift -> 2-way conflicts
// only, free). A frags stream from global (f16, one b128 = one frag) with a
// 1-step register prefetch. Wave: 4x8 grid of 16x16x32 tiles over K=256.
//   A frag: lane holds A[m0+64w+16i + (lane&15)][32ks + quad*8 .. +7]
//   B frag: lane holds WT[n0+16j + (lane&15)][32ks + quad*8 .. +7]
//   C/D:    reg r -> C[.. 16i + quad*4 + r][.. 16j + (lane&15)]
// Tail rows clamped on load, guarded on store.
// ---------------------------------------------------------------------------
template <int NC>
__global__ __launch_bounds__(256, 2) void gemm2(
    const _Float16* __restrict__ A, const _Float16* __restrict__ WT,
    const float* __restrict__ bias, _Float16* __restrict__ C, int M) {
  __shared__ _Float16 bs[128 * 264];   // 264 = 256 + 8 pad
  const int t = threadIdx.x;
  const int wave = t >> 6, lane = t & 63;
  const int l15 = lane & 15, quad = lane >> 4;
  const int m0 = blockIdx.x * 256 + wave * 64;
  const int n0 = blockIdx.y * 128;

  // ---- fill B slab: 4096 16B-chunks, thread t -> chunks t, t+256, ...
  #pragma unroll
  for (int j = 0; j < 16; ++j) {
    const int c = t + 256 * j;
    const int n = c >> 5, ck = c & 31;
    *(half8*)&bs[n * 264 + ck * 8] =
        *(const half8*)(WT + (size_t)(n0 + n) * 256 + ck * 8);
  }

  const _Float16* Ab[4];
  #pragma unroll
  for (int i = 0; i < 4; ++i) {
    const int row = min(m0 + 16 * i + l15, M - 1);
    Ab[i] = A + (size_t)row * 256 + quad * 8;
  }
  float bcol[8];
  #pragma unroll
  for (int j = 0; j < 8; ++j) bcol[j] = bias[n0 + 16 * j + l15];

  floatx4 acc[4][8] = {};
  half8 ar[4], an[4];
  #pragma unroll
  for (int i = 0; i < 4; ++i) ar[i] = *(const half8*)(Ab[i]);

  __syncthreads();

  const int koff = quad * 8;
  #pragma unroll
  for (int ks = 0; ks < 8; ++ks) {
    if (ks < 7) {
      #pragma unroll
      for (int i = 0; i < 4; ++i) an[i] = *(const half8*)(Ab[i] + (ks + 1) * 32);
    }
    #pragma unroll
    for (int j = 0; j < 8; ++j) {
      const half8 b = *(const half8*)&bs[(16 * j + l15) * 264 + ks * 32 + koff];
      #pragma unroll
      for (int i = 0; i < 4; ++i)
        acc[i][j] = __builtin_amdgcn_mfma_f32_16x16x32_f16(ar[i], b, acc[i][j], 0, 0, 0);
    }
    #pragma unroll
    for (int i = 0; i < 4; ++i) ar[i] = an[i];
  }

  #pragma unroll
  for (int i = 0; i < 4; ++i) {
    #pragma unroll
    for (int r = 0; r < 4; ++r) {
      const int row = m0 + 16 * i + quad * 4 + r;
      if (row < M) {
        #pragma unroll
        for (int j = 0; j < 8; ++j)
          C[(size_t)row * NC + n0 + 16 * j + l15] =
              (_Float16)(acc[i][j][r] + bcol[j]);
      }
    }
  }
}

// ---------------------------------------------------------------------------
// Fused softmax + deformable bilinear sampling.
// One block per (b,q). Phase 1: thread t = (h,l,p) -> softmax weight (xor
// shuffles), 4 gather offsets + 4 bilinear*attn weights into LDS.
// Phase 2: within each 32-lane head group, lane g = (cq, cr, pp):
//   cq = g&3  channel quad (8 ch), cr = (g>>2)&3 corner, pp = g>>4 point
//   parity. Loop 16 points (2i+pp): ONE half8 global load per lane per
//   point (4x fewer VMEM instrs than round 3), 8 fma into f32 acc.
// Epilogue: xor-shuffle reduce over {4,8,16}, lanes g<4 write float4 x2.
// ---------------------------------------------------------------------------
__global__ __launch_bounds__(256) void msda_sample(
    const _Float16* __restrict__ vproj,     // [B*S, 256] f16 (d fastest)
    const _Float16* __restrict__ fused,     // [B*Q, 768] f16: off(512)|logit(256)
    const float* __restrict__ ref,          // [B*Q, 4, 2] f32
    float* __restrict__ out) {              // [B*Q, 256] f32
  const int lvl_h[NL] = {92, 46, 23, 12};
  const int lvl_w[NL] = {160, 80, 40, 20};
  const int lvl_s[NL] = {0, 14720, 18400, 19320};

  __shared__ float4 w_s[256];
  __shared__ int4   a_s[256];

  const int t   = threadIdx.x;
  const int row = blockIdx.x;          // b*NQ + q
  const int b   = row / NQ;

  const int h  = t >> 5;
  const int lp = t & 31;
  const int l  = lp >> 3;
  const int p  = lp & 7;

  // ---- softmax over the 32 (l,p) logits of this head (xor shuffles) ----
  const float logit = (float)fused[(size_t)row * 768 + 512 + t];
  float mx = logit;
  #pragma unroll
  for (int m = 1; m < 32; m <<= 1) mx = fmaxf(mx, __shfl_xor(mx, m));
  const float e = __expf(logit - mx);
  float sum = e;
  #pragma unroll
  for (int m = 1; m < 32; m <<= 1) sum += __shfl_xor(sum, m);
  const float attnw = e / sum;

  // ---- location & bilinear setup ----
  const half2v o2 = *(const half2v*)(fused + (size_t)row * 768 + 2 * t);
  const float ox = (float)o2[0], oy = (float)o2[1];
  const int z = p & 3;                       // NP=8 split (2,4): z = p % 4
  const float rx = ref[((size_t)row * 4 + z) * 2 + 0];
  const float ry = ref[((size_t)row * 4 + z) * 2 + 1];
  const int Wl = lvl_w[l], Hl = lvl_h[l], st = lvl_s[l];

  const float px = fmaf(rx, (float)Wl, ox) - 0.5f;
  const float py = fmaf(ry, (float)Hl, oy) - 0.5f;
  const float x0f = floorf(px), y0f = floorf(py);
  const float wx = px - x0f, wy = py - y0f;
  const int x0 = (int)x0f, y0 = (int)y0f;
  const int x1 = x0 + 1,   y1 = y0 + 1;

  const float mx0 = (x0 >= 0 && x0 < Wl) ? 1.f : 0.f;
  const float mx1 = (x1 >= 0 && x1 < Wl) ? 1.f : 0.f;
  const float my0 = (y0 >= 0 && y0 < Hl) ? 1.f : 0.f;
  const float my1 = (y1 >= 0 && y1 < Hl) ? 1.f : 0.f;
  const int cx0 = min(max(x0, 0), Wl - 1), cx1 = min(max(x1, 0), Wl - 1);
  const int cy0 = min(max(y0, 0), Hl - 1), cy1 = min(max(y1, 0), Hl - 1);

  const int base = b * S_TOTAL + st;
  const int hoff = h << 5;
  int4 a4;
  a4.x = (base + cy0 * Wl + cx0) * 256 + hoff;
  a4.y = (base + cy0 * Wl + cx1) * 256 + hoff;
  a4.z = (base + cy1 * Wl + cx0) * 256 + hoff;
  a4.w = (base + cy1 * Wl + cx1) * 256 + hoff;

  float4 w4;
  w4.x = attnw * (1.f - wx) * (1.f - wy) * mx0 * my0;
  w4.y = attnw * wx * (1.f - wy) * mx1 * my0;
  w4.z = attnw * (1.f - wx) * wy * mx0 * my1;
  w4.w = attnw * wx * wy * mx1 * my1;

  w_s[t] = w4;
  a_s[t] = a4;
  __syncthreads();

  // ---- phase 2: lane g = (cq, cr, pp) within head group ----
  const int g  = t & 31;
  const int cq = g & 3;
  const int cr = (g >> 2) & 3;
  const int pp = g >> 4;
  const int* a_flat = (const int*)a_s;
  const float* w_flat = (const float*)w_s;

  float acc8[8] = {};
  #pragma unroll 8
  for (int i = 0; i < 16; ++i) {
    const int pt = (h << 5) + 2 * i + pp;
    const int addr = a_flat[pt * 4 + cr];
    const float w  = w_flat[pt * 4 + cr];
    const half8 v = *(const half8*)(vproj + addr + 8 * cq);
    #pragma unroll
    for (int c = 0; c < 8; ++c) acc8[c] = fmaf(w, (float)v[c], acc8[c]);
  }

  // reduce over corner (xor 4, 8) and point parity (xor 16)
  #pragma unroll
  for (int c = 0; c < 8; ++c) {
    acc8[c] += __shfl_xor(acc8[c], 4);
    acc8[c] += __shfl_xor(acc8[c], 8);
    acc8[c] += __shfl_xor(acc8[c], 16);
  }
  if ((g & 28) == 0) {   // cr==0 && pp==0: lanes g=0..3 own channel quads
    float* op = out + (size_t)row * 256 + hoff + 8 * cq;
    float4 o0, o1;
    o0.x = acc8[0]; o0.y = acc8[1]; o0.z = acc8[2]; o0.w = acc8[3];
    o1.x = acc8[4]; o1.y = acc8[5]; o1.z = acc8[6]; o1.w = acc8[7];
    *(float4*)op = o0;
    *(float4*)(op + 4) = o1;
  }
}

extern "C" void kernel_launch(void* const* d_in, const int* in_sizes, int n_in,
                              void* d_out, int out_size, void* d_ws, size_t ws_size,
                              hipStream_t stream) {
  const float* query  = (const float*)d_in[0];  // [4,10000,256]
  const float* value  = (const float*)d_in[1];  // [4,19560,256]
  const float* refpts = (const float*)d_in[2];  // [4,10000,4,2]
  const float* w_off  = (const float*)d_in[3];  // [256,512]
  const float* b_off  = (const float*)d_in[4];  // [512]
  const float* w_attn = (const float*)d_in[5];  // [256,256]
  const float* b_attn = (const float*)d_in[6];  // [256]
  const float* w_val  = (const float*)d_in[7];  // [256,256]
  const float* b_val  = (const float*)d_in[8];  // [256]
  float* out = (float*)d_out;

  // workspace layout (all segment sizes 16B-multiples)
  char* p = (char*)d_ws;
  _Float16* qh    = (_Float16*)p;  p += (size_t)NROW * 256 * 2;     // 20.5 MB
  _Float16* vah   = (_Float16*)p;  p += (size_t)VROWS * 256 * 2;    // 40.1 MB
  _Float16* vh    = (_Float16*)p;  p += (size_t)VROWS * 256 * 2;    // 40.1 MB
  _Float16* wT768 = (_Float16*)p;  p += (size_t)768 * 256 * 2;
  _Float16* wvaT  = (_Float16*)p;  p += (size_t)256 * 256 * 2;
  float*    bias768 = (float*)p;   p += 768 * 4;
  _Float16* fused_h = (_Float16*)p; p += (size_t)NROW * 768 * 2;    // 61.4 MB

  // prep: f32->f16 A copies, weight transposes, fused bias
  conv_f16<<<(NROW * 256 / 8 + 255) / 256, 256, 0, stream>>>(
      query, qh, (size_t)NROW * 256);
  conv_f16<<<(VROWS * 256 / 8 + 255) / 256, 256, 0, stream>>>(
      value, vah, (size_t)VROWS * 256);
  transp_f16<<<512, 256, 0, stream>>>(w_off, wT768, 512);          // rows 0..511
  transp_f16<<<256, 256, 0, stream>>>(w_attn, wT768 + 512 * 256, 256); // rows 512..767
  transp_f16<<<256, 256, 0, stream>>>(w_val, wvaT, 256);
  bias_cat<<<3, 256, 0, stream>>>(b_off, b_attn, bias768);

  // GEMMs: v = value@w_val (NC=256), fused = query@[w_off|w_attn] (NC=768)
  gemm2<256><<<dim3((VROWS + 255) / 256, 2), 256, 0, stream>>>(
      vah, wvaT, b_val, vh, VROWS);
  gemm2<768><<<dim3((NROW + 255) / 256, 6), 256, 0, stream>>>(
      qh, wT768, bias768, fused_h, NROW);

  // softmax + sample + weighted sum
  msda_sample<<<dim3(NROW), 256, 0, stream>>>(vh, fused_h, refpts, out);
}

// Round 5
// 466.747 us; speedup vs baseline: 2.2260x; 1.0569x over previous
//
#include <hip/hip_runtime.h>

// Problem constants (fixed by setup_inputs)
#define BATCH    4
#define NQ       10000
#define EMB      256
#define NH       8
#define DH       32
#define NL       4
#define NP       8
#define S_TOTAL  19560
#define NROW     (BATCH * NQ)          // 40000
#define VROWS    (BATCH * S_TOTAL)     // 78240

typedef _Float16 half8 __attribute__((ext_vector_type(8)));
typedef _Float16 half4v __attribute__((ext_vector_type(4)));
typedef _Float16 half2v __attribute__((ext_vector_type(2)));
typedef float floatx4 __attribute__((ext_vector_type(4)));

// ---------------------------------------------------------------------------
// f32 -> f16 row-major copy. 8 elems per thread.
// ---------------------------------------------------------------------------
__global__ __launch_bounds__(256) void conv_f16(
    const float* __restrict__ in, _Float16* __restrict__ out, size_t total) {
  const size_t e = ((size_t)blockIdx.x * 256 + threadIdx.x) * 8;
  if (e >= total) return;
  const float4 f0 = *(const float4*)(in + e);
  const float4 f1 = *(const float4*)(in + e + 4);
  half8 h;
  h[0] = (_Float16)f0.x; h[1] = (_Float16)f0.y;
  h[2] = (_Float16)f0.z; h[3] = (_Float16)f0.w;
  h[4] = (_Float16)f1.x; h[5] = (_Float16)f1.y;
  h[6] = (_Float16)f1.z; h[7] = (_Float16)f1.w;
  *(half8*)(out + e) = h;
}

// ---------------------------------------------------------------------------
// W[256,N] f32 -> WT[N,256] f16
// ---------------------------------------------------------------------------
__global__ __launch_bounds__(256) void transp_f16(
    const float* __restrict__ W, _Float16* __restrict__ WT, int N) {
  const int tid = blockIdx.x * 256 + threadIdx.x;   // over N*256
  const int n = tid >> 8, k = tid & 255;
  WT[(size_t)n * 256 + k] = (_Float16)W[(size_t)k * N + n];
}

// fused bias [768] = concat(b_off[512], b_attn[256])
__global__ __launch_bounds__(256) void bias_cat(
    const float* __restrict__ b0, const float* __restrict__ b1,
    float* __restrict__ o) {
  const int t = blockIdx.x * 256 + threadIdx.x;
  if (t < 512) o[t] = b0[t];
  else if (t < 768) o[t] = b1[t - 512];
}

// ---------------------------------------------------------------------------
// MFMA GEMM, B-slab-in-LDS: C = A[M,256]_f16 @ WT[NC,256]^T + bias.
// Block 256 thr = 4 row-stacked waves; block tile 256 rows x 128 cols.
// B slab (128x256 f16, +8/row pad) in LDS. A frags from global with a
// 2-deep register prefetch ring (covers global latency across 2 MFMA
// rounds). Wave: 4x8 grid of 16x16x32 tiles, K=256.
// SWZ=true writes v in [B, H, S, D] layout: dest = ((b*8+h)*S + s)*32 + d.
// ---------------------------------------------------------------------------
template <int NC, bool SWZ>
__global__ __launch_bounds__(256, 2) void gemm2(
    const _Float16* __restrict__ A, const _Float16* __restrict__ WT,
    const float* __restrict__ bias, _Float16* __restrict__ C, int M) {
  __shared__ _Float16 bs[128 * 264];   // 264 = 256 + 8 pad
  const int t = threadIdx.x;
  const int wave = t >> 6, lane = t & 63;
  const int l15 = lane & 15, quad = lane >> 4;
  const int m0 = blockIdx.x * 256 + wave * 64;
  const int n0 = blockIdx.y * 128;

  // ---- fill B slab: 4096 16B-chunks, thread t -> chunks t, t+256, ...
  #pragma unroll
  for (int j = 0; j < 16; ++j) {
    const int c = t + 256 * j;
    const int n = c >> 5, ck = c & 31;
    *(half8*)&bs[n * 264 + ck * 8] =
        *(const half8*)(WT + (size_t)(n0 + n) * 256 + ck * 8);
  }

  const _Float16* Ab[4];
  #pragma unroll
  for (int i = 0; i < 4; ++i) {
    const int row = min(m0 + 16 * i + l15, M - 1);
    Ab[i] = A + (size_t)row * 256 + quad * 8;
  }
  float bcol[8];
  #pragma unroll
  for (int j = 0; j < 8; ++j) bcol[j] = bias[n0 + 16 * j + l15];

  floatx4 acc[4][8] = {};
  half8 ring[2][4];
  #pragma unroll
  for (int i = 0; i < 4; ++i) ring[0][i] = *(const half8*)(Ab[i]);
  #pragma unroll
  for (int i = 0; i < 4; ++i) ring[1][i] = *(const half8*)(Ab[i] + 32);

  __syncthreads();

  const int koff = quad * 8;
  #pragma unroll
  for (int ks = 0; ks < 8; ++ks) {
    half8 cur[4];
    #pragma unroll
    for (int i = 0; i < 4; ++i) cur[i] = ring[ks & 1][i];
    if (ks < 6) {
      #pragma unroll
      for (int i = 0; i < 4; ++i)
        ring[ks & 1][i] = *(const half8*)(Ab[i] + (ks + 2) * 32);
    }
    #pragma unroll
    for (int j = 0; j < 8; ++j) {
      const half8 b = *(const half8*)&bs[(16 * j + l15) * 264 + ks * 32 + koff];
      #pragma unroll
      for (int i = 0; i < 4; ++i)
        acc[i][j] = __builtin_amdgcn_mfma_f32_16x16x32_f16(cur[i], b, acc[i][j], 0, 0, 0);
    }
  }

  #pragma unroll
  for (int i = 0; i < 4; ++i) {
    #pragma unroll
    for (int r = 0; r < 4; ++r) {
      const int row = m0 + 16 * i + quad * 4 + r;
      if (row < M) {
        if (SWZ) {
          const int b = row / S_TOTAL;
          const int s = row - b * S_TOTAL;
          #pragma unroll
          for (int j = 0; j < 8; ++j) {
            const int col = n0 + 16 * j + l15;
            const size_t dst =
                (((size_t)b * NH + (col >> 5)) * S_TOTAL + s) * 32 + (col & 31);
            C[dst] = (_Float16)(acc[i][j][r] + bcol[j]);
          }
        } else {
          #pragma unroll
          for (int j = 0; j < 8; ++j)
            C[(size_t)row * NC + n0 + 16 * j + l15] =
                (_Float16)(acc[i][j][r] + bcol[j]);
        }
      }
    }
  }
}

// ---------------------------------------------------------------------------
// Fused softmax + deformable bilinear sampling. vproj layout [B,H,S,32]:
// the (y,x0)/(y,x1) corner pair is 128 B contiguous -> 2 segments per point.
// Grid remap: blk = b + 4*qidx so XCD k (round-robin blk%8) sees only
// batch k&3 -> per-XCD v working set 10 MB instead of 40.
// Phase 1: thread t=(h,l,p) -> softmax (xor-shuffles), then for each of 2
// row-pairs: clamped base addr + left/right corner weights into LDS.
// Phase 2: 32-lane head group, lane = (ph, side, chquad): per point-half,
// 2 half4 loads (top/bottom rowpair), 4 fma each; unroll 8 -> 16 loads in
// flight per lane. Reduce over side (xor 8) and ph (xor 16).
// ---------------------------------------------------------------------------
__global__ __launch_bounds__(256) void msda_sample(
    const _Float16* __restrict__ vproj,     // [B,H,S,32] f16 (+guards)
    const _Float16* __restrict__ fused,     // [B*Q, 768] f16: off(512)|logit(256)
    const float* __restrict__ ref,          // [B*Q, 4, 2] f32
    float* __restrict__ out) {              // [B*Q, 256] f32
  const int lvl_h[NL] = {92, 46, 23, 12};
  const int lvl_w[NL] = {160, 80, 40, 20};
  const int lvl_s[NL] = {0, 14720, 18400, 19320};

  __shared__ int   addr_s[512];   // [(h*32+p)*2 + rp]
  __shared__ float wl_s[512];
  __shared__ float wr_s[512];

  const int t   = threadIdx.x;
  const int blk = blockIdx.x;
  const int b   = blk & 3;             // pins batch to XCD (blk%8 round-robin)
  const int q   = blk >> 2;
  const int row = b * NQ + q;

  const int h  = t >> 5;
  const int lp = t & 31;
  const int l  = lp >> 3;
  const int p  = lp & 7;

  // ---- softmax over the 32 (l,p) logits of this head (xor shuffles) ----
  const float logit = (float)fused[(size_t)row * 768 + 512 + t];
  float mxv = logit;
  #pragma unroll
  for (int m = 1; m < 32; m <<= 1) mxv = fmaxf(mxv, __shfl_xor(mxv, m));
  const float e = __expf(logit - mxv);
  float sum = e;
  #pragma unroll
  for (int m = 1; m < 32; m <<= 1) sum += __shfl_xor(sum, m);
  const float attnw = e / sum;

  // ---- location & bilinear setup ----
  const half2v o2 = *(const half2v*)(fused + (size_t)row * 768 + 2 * t);
  const float ox = (float)o2[0], oy = (float)o2[1];
  const int z = p & 3;                       // NP=8 split (2,4): z = p % 4
  const float rx = ref[((size_t)row * 4 + z) * 2 + 0];
  const float ry = ref[((size_t)row * 4 + z) * 2 + 1];
  const int Wl = lvl_w[l], Hl = lvl_h[l], st = lvl_s[l];

  const float px = fmaf(rx, (float)Wl, ox) - 0.5f;
  const float py = fmaf(ry, (float)Hl, oy) - 0.5f;
  const float x0f = floorf(px), y0f = floorf(py);
  const float wx = px - x0f, wy = py - y0f;
  const int x0 = (int)x0f, y0 = (int)y0f;
  const int x1 = x0 + 1,   y1 = y0 + 1;

  // x: one 128B segment based at xb covers slots xb (left) and xb+1 (right)
  const float mx0 = (x0 >= 0 && x0 < Wl) ? 1.f : 0.f;
  const float mx1 = (x1 >= 0 && x1 < Wl) ? 1.f : 0.f;
  const float my0 = (y0 >= 0 && y0 < Hl) ? 1.f : 0.f;
  const float my1 = (y1 >= 0 && y1 < Hl) ? 1.f : 0.f;
  const int xb  = min(max(x0, -1), Wl - 1);          // guard pages cover x=-1/W
  const int cy0 = min(max(y0, 0), Hl - 1);
  const int cy1 = min(max(y1, 0), Hl - 1);

  const int bh   = b * NH + h;
  const int lbase = bh * S_TOTAL + st;
  const float wlc = attnw * (1.f - wx) * mx0;
  const float wrc = attnw * wx * mx1;

  addr_s[2 * t + 0] = (lbase + cy0 * Wl + xb) * 32;
  addr_s[2 * t + 1] = (lbase + cy1 * Wl + xb) * 32;
  wl_s[2 * t + 0] = wlc * (1.f - wy) * my0;
  wr_s[2 * t + 0] = wrc * (1.f - wy) * my0;
  wl_s[2 * t + 1] = wlc * wy * my1;
  wr_s[2 * t + 1] = wrc * wy * my1;
  __syncthreads();

  // ---- phase 2: lane g = (ph, side, chquad) within head group ----
  const int g  = t & 31;
  const int c  = g & 7;           // channel quad: channels 4c..4c+3
  const int sd = (g >> 3) & 1;    // 0 = left corner, 1 = right corner
  const int ph = g >> 4;          // point parity
  const int ldoff = sd * 32 + 4 * c;

  float a0 = 0.f, a1 = 0.f, a2 = 0.f, a3 = 0.f;
  #pragma unroll 8
  for (int i = 0; i < 16; ++i) {
    const int idx = ((h << 5) + 2 * i + ph) * 2;
    const int at = addr_s[idx],     ab = addr_s[idx + 1];
    const float wt = sd ? wr_s[idx]     : wl_s[idx];
    const float wb = sd ? wr_s[idx + 1] : wl_s[idx + 1];
    const half4v vt = *(const half4v*)(vproj + at + ldoff);
    const half4v vb = *(const half4v*)(vproj + ab + ldoff);
    a0 = fmaf(wt, (float)vt[0], a0); a1 = fmaf(wt, (float)vt[1], a1);
    a2 = fmaf(wt, (float)vt[2], a2); a3 = fmaf(wt, (float)vt[3], a3);
    a0 = fmaf(wb, (float)vb[0], a0); a1 = fmaf(wb, (float)vb[1], a1);
    a2 = fmaf(wb, (float)vb[2], a2); a3 = fmaf(wb, (float)vb[3], a3);
  }

  // reduce over side (xor 8) and point parity (xor 16)
  a0 += __shfl_xor(a0, 8);  a1 += __shfl_xor(a1, 8);
  a2 += __shfl_xor(a2, 8);  a3 += __shfl_xor(a3, 8);
  a0 += __shfl_xor(a0, 16); a1 += __shfl_xor(a1, 16);
  a2 += __shfl_xor(a2, 16); a3 += __shfl_xor(a3, 16);

  if (g < 8) {    // sd==0 && ph==0: 8 lanes own the 8 channel quads
    float4 o; o.x = a0; o.y = a1; o.z = a2; o.w = a3;
    *(float4*)(out + (size_t)row * 256 + (h << 5) + 4 * c) = o;
  }
}

extern "C" void kernel_launch(void* const* d_in, const int* in_sizes, int n_in,
                              void* d_out, int out_size, void* d_ws, size_t ws_size,
                              hipStream_t stream) {
  const float* query  = (const float*)d_in[0];  // [4,10000,256]
  const float* value  = (const float*)d_in[1];  // [4,19560,256]
  const float* refpts = (const float*)d_in[2];  // [4,10000,4,2]
  const float* w_off  = (const float*)d_in[3];  // [256,512]
  const float* b_off  = (const float*)d_in[4];  // [512]
  const float* w_attn = (const float*)d_in[5];  // [256,256]
  const float* b_attn = (const float*)d_in[6];  // [256]
  const float* w_val  = (const float*)d_in[7];  // [256,256]
  const float* b_val  = (const float*)d_in[8];  // [256]
  float* out = (float*)d_out;

  // workspace layout (16B-multiple segments; 256B guards around vh for the
  // x=-1 / x=W edge reads, whose weights are zero)
  char* p = (char*)d_ws;
  _Float16* qh    = (_Float16*)p;  p += (size_t)NROW * 256 * 2;     // 20.5 MB
  _Float16* vah   = (_Float16*)p;  p += (size_t)VROWS * 256 * 2;    // 40.1 MB
  p += 256;                                                         // front guard
  _Float16* vh    = (_Float16*)p;  p += (size_t)VROWS * 256 * 2;    // 40.1 MB
  p += 256;                                                         // back guard
  _Float16* wT768 = (_Float16*)p;  p += (size_t)768 * 256 * 2;
  _Float16* wvaT  = (_Float16*)p;  p += (size_t)256 * 256 * 2;
  float*    bias768 = (float*)p;   p += 768 * 4;
  _Float16* fused_h = (_Float16*)p; p += (size_t)NROW * 768 * 2;    // 61.4 MB

  // prep: f32->f16 A copies, weight transposes, fused bias
  conv_f16<<<(NROW * 256 / 8 + 255) / 256, 256, 0, stream>>>(
      query, qh, (size_t)NROW * 256);
  conv_f16<<<(VROWS * 256 / 8 + 255) / 256, 256, 0, stream>>>(
      value, vah, (size_t)VROWS * 256);
  transp_f16<<<512, 256, 0, stream>>>(w_off, wT768, 512);
  transp_f16<<<256, 256, 0, stream>>>(w_attn, wT768 + 512 * 256, 256);
  transp_f16<<<256, 256, 0, stream>>>(w_val, wvaT, 256);
  bias_cat<<<3, 256, 0, stream>>>(b_off, b_attn, bias768);

  // GEMMs: v = value@w_val -> [B,H,S,32] swizzled; fused = query@[w_off|w_attn]
  gemm2<256, true><<<dim3((VROWS + 255) / 256, 2), 256, 0, stream>>>(
      vah, wvaT, b_val, vh, VROWS);
  gemm2<768, false><<<dim3((NROW + 255) / 256, 6), 256, 0, stream>>>(
      qh, wT768, bias768, fused_h, NROW);

  // softmax + sample + weighted sum
  msda_sample<<<dim3(NROW), 256, 0, stream>>>(vh, fused_h, refpts, out);
}